// Round 6
// baseline (418.105 us; speedup 1.0000x reference)
//
#include <hip/hip_runtime.h>

typedef __bf16 bf16;
typedef __bf16 bf16x8 __attribute__((ext_vector_type(8)));
typedef float floatx4 __attribute__((ext_vector_type(4)));

#define BATCH 128
#define SEQ   2048
#define HID   128
#define TWOH  256
#define CH    128
#define NCH   16
#define MTOT  (BATCH * SEQ)    // 262144

__device__ __forceinline__ float fast_tanh(float x) {
    float e = __builtin_amdgcn_exp2f(2.88539008177793f * x);
    return 1.0f - 2.0f * __builtin_amdgcn_rcpf(e + 1.0f);
}
__device__ __forceinline__ float fast_sigmoid(float x) {
    return __builtin_amdgcn_rcpf(1.0f + __builtin_amdgcn_exp2f(-1.44269504088896f * x));
}

union PK4 { unsigned long long u; bf16 h[4]; };
union PK8 { uint4 u; bf16 h[8]; bf16x8 v; };

// ---- one-time f32 -> bf16 conversion of Wx2h, PRE-SWIZZLED for LDS ----
// dst[R*128 + ((g ^ (n&7))<<3) + j] = W[R][g*8+j], n = R&127.
__global__ __launch_bounds__(256) void convert_w_k(const float* __restrict__ W,
                                                   bf16* __restrict__ Wb) {
    int i = blockIdx.x * 256 + threadIdx.x;   // 16384 float4 groups
    float4 v = ((const float4*)W)[i];
    int R  = i >> 5;            // row 0..511
    int k0 = (i & 31) << 2;     // col 0,4,...,124
    int n  = R & 127;
    int g  = k0 >> 3;
    int j0 = k0 & 7;            // 0 or 4
    PK4 pk;
    pk.h[0] = (bf16)v.x; pk.h[1] = (bf16)v.y;
    pk.h[2] = (bf16)v.z; pk.h[3] = (bf16)v.w;
    *(unsigned long long*)&Wb[R * 128 + ((g ^ (n & 7)) << 3) + j0] = pk.u;
}

// In-tile inclusive prefix over the 128 rows of a chunk, one column set.
__device__ __forceinline__ void tile_prefix(const float g[4][4], float pref[4][4],
                                            float* stripe_tot, int quad, int l16) {
    float mibase = 0.f;
    #pragma unroll
    for (int mi = 0; mi < 4; ++mi) {
        float s0 = g[mi][0];
        float s1 = s0 + g[mi][1];
        float s2 = s1 + g[mi][2];
        float s3 = s2 + g[mi][3];
        float tot = s3, xq = tot;
        float t = __shfl_up(xq, 16);
        if (quad >= 1) xq += t;
        t = __shfl_up(xq, 32);
        if (quad >= 2) xq += t;
        float excl = mibase + xq - tot;
        pref[mi][0] = excl + s0;
        pref[mi][1] = excl + s1;
        pref[mi][2] = excl + s2;
        pref[mi][3] = excl + s3;
        mibase += __shfl(xq, 48 + l16);   // quad-3 inclusive total
    }
    *stripe_tot = mibase;
}

// Load one MFMA A-fragment (8 consecutive f32) from global, convert to bf16x8.
__device__ __forceinline__ bf16x8 ldAf(const float* __restrict__ p) {
    float4 a0 = *(const float4*)p;
    float4 a1 = *(const float4*)(p + 4);
    bf16x8 r;
    r[0] = (bf16)a0.x; r[1] = (bf16)a0.y; r[2] = (bf16)a0.z; r[3] = (bf16)a0.w;
    r[4] = (bf16)a1.x; r[5] = (bf16)a1.y; r[6] = (bf16)a1.z; r[7] = (bf16)a1.w;
    return r;
}

// MFMA over one 128x128(xK=128) half, A and B both from LDS (swizzled).
__device__ __forceinline__ void gemm_tile(const bf16* As, const bf16* Bs,
                                          floatx4 acc[4][2], int wr, int wc,
                                          int quad, int l16) {
    #pragma unroll
    for (int s = 0; s < 4; ++s) {
        int kg = s * 4 + quad;
        bf16x8 af[4], bfr[2];
        #pragma unroll
        for (int mi = 0; mi < 4; ++mi) {
            int r = wr * 64 + mi * 16 + l16;
            af[mi] = *(const bf16x8*)&As[r * 128 + ((kg ^ (r & 7)) << 3)];
        }
        #pragma unroll
        for (int ni = 0; ni < 2; ++ni) {
            int n = wc * 32 + ni * 16 + l16;
            bfr[ni] = *(const bf16x8*)&Bs[n * 128 + ((kg ^ (n & 7)) << 3)];
        }
        #pragma unroll
        for (int mi = 0; mi < 4; ++mi)
            #pragma unroll
            for (int ni = 0; ni < 2; ++ni)
                acc[mi][ni] = __builtin_amdgcn_mfma_f32_16x16x32_bf16(
                    af[mi], bfr[ni], acc[mi][ni], 0, 0, 0);
    }
}

__device__ __forceinline__ void decode_T(const uint4 tr[4], float g2[2][4][4]) {
    #pragma unroll
    for (int mi = 0; mi < 4; ++mi) {
        PK8 p;
        p.u = tr[mi];
        #pragma unroll
        for (int rr = 0; rr < 4; ++rr) {
            g2[0][mi][rr] = (float)p.h[rr];
            g2[1][mi][rr] = (float)p.h[4 + rr];
        }
    }
}

__device__ __forceinline__ void store_T_half(uint4* __restrict__ T, long blk,
                                             int half, int tid, const float g2[2][4][4]) {
    #pragma unroll
    for (int mi = 0; mi < 4; ++mi) {
        PK8 p;
        #pragma unroll
        for (int rr = 0; rr < 4; ++rr) {
            p.h[rr]     = (bf16)g2[0][mi][rr];
            p.h[4 + rr] = (bf16)g2[1][mi][rr];
        }
        T[((blk * 2 + half) * 4 + mi) * 512 + tid] = p.u;
    }
}

// ===========================================================================
// Geometry: 512 threads = 8 waves, wr = wid>>2 (row 64-stripe), wc = wid&3
// (col 32-stripe per half). C row = wr*64+mi*16+quad*4+rr,
// col = half*128+wc*32+ni*16+l16.
// EARLY-EXIT: chunks with cc*128 >= xlen[bb] affect nothing downstream.
// ===========================================================================

// ---- K1: layer-0 GEMM (A direct from global!); tanh frags + chunk sums ----
__global__ __launch_bounds__(512, 4) void l0_k(const float* __restrict__ x,
                                               const bf16* __restrict__ Wbs,
                                               uint4* __restrict__ T,
                                               float* __restrict__ Pout,
                                               const int* __restrict__ xlen) {
    __shared__ bf16 Bs[128 * 128];          // 32 KB (only LDS tile)
    __shared__ float psum[512];

    const int tid  = threadIdx.x;
    const int lane = tid & 63;
    const int wid  = tid >> 6;
    const int wr   = wid >> 2;
    const int wc   = wid & 3;
    const int quad = lane >> 4;
    const int l16  = lane & 15;
    const long blk = blockIdx.x;
    const int  bb  = (int)(blk >> 4);
    const int  cc  = (int)(blk & 15);
    if ((cc << 7) >= xlen[bb]) return;      // uniform early-exit, before barriers

    // per-thread A base: rows wr*64 + mi*16 + l16 of this chunk
    const float* ab = x + ((size_t)blk * 128 + (size_t)(wr * 64 + l16)) * HID;

    // W0 -> Bs (pre-swizzled -> linear copy); then issue W1 loads into regs
    uint4 wv[4];
    {
        const uint4* W8 = (const uint4*)Wbs;
        #pragma unroll
        for (int it = 0; it < 4; ++it) wv[it] = W8[it * 512 + tid];
        #pragma unroll
        for (int it = 0; it < 4; ++it)
            *(uint4*)&Bs[(it * 512 + tid) * 8] = wv[it];
        const uint4* W81 = (const uint4*)(Wbs + 128 * HID);
        #pragma unroll
        for (int it = 0; it < 4; ++it) wv[it] = W81[it * 512 + tid];
    }
    __syncthreads();                         // Bs(W0) ready

    #pragma unroll
    for (int half = 0; half < 2; ++half) {
        floatx4 acc[4][2];
        #pragma unroll
        for (int a = 0; a < 4; ++a)
            #pragma unroll
            for (int b2 = 0; b2 < 2; ++b2) acc[a][b2] = (floatx4){0.f, 0.f, 0.f, 0.f};

        // A from global with 2-deep prefetch (half1 re-reads are L2/L3 hits)
        bf16x8 af2[2][4];
        #pragma unroll
        for (int mi = 0; mi < 4; ++mi)
            af2[0][mi] = ldAf(ab + (size_t)mi * 16 * HID + quad * 8);
        #pragma unroll
        for (int s = 0; s < 4; ++s) {
            int kg = s * 4 + quad;
            if (s < 3) {
                #pragma unroll
                for (int mi = 0; mi < 4; ++mi)
                    af2[(s + 1) & 1][mi] =
                        ldAf(ab + (size_t)mi * 16 * HID + (kg + 4) * 8);
            }
            bf16x8 bfr[2];
            #pragma unroll
            for (int ni = 0; ni < 2; ++ni) {
                int n = wc * 32 + ni * 16 + l16;
                bfr[ni] = *(const bf16x8*)&Bs[n * 128 + ((kg ^ (n & 7)) << 3)];
            }
            #pragma unroll
            for (int mi = 0; mi < 4; ++mi)
                #pragma unroll
                for (int ni = 0; ni < 2; ++ni)
                    acc[mi][ni] = __builtin_amdgcn_mfma_f32_16x16x32_bf16(
                        af2[s & 1][mi], bfr[ni], acc[mi][ni], 0, 0, 0);
        }

        if (half == 0) {
            __syncthreads();                 // Bs(W0) reads done
            #pragma unroll
            for (int it = 0; it < 4; ++it)
                *(uint4*)&Bs[(it * 512 + tid) * 8] = wv[it];   // W1 -> Bs
        }

        float g2[2][4][4];   // [ni][mi][rr]
        #pragma unroll
        for (int mi = 0; mi < 4; ++mi)
            #pragma unroll
            for (int ni = 0; ni < 2; ++ni)
                #pragma unroll
                for (int rr = 0; rr < 4; ++rr)
                    g2[ni][mi][rr] = fast_tanh(acc[mi][ni][rr]);

        store_T_half(T, blk, half, tid, g2);

        #pragma unroll
        for (int ni = 0; ni < 2; ++ni) {
            float cs = 0.f;
            #pragma unroll
            for (int mi = 0; mi < 4; ++mi)
                #pragma unroll
                for (int rr = 0; rr < 4; ++rr) cs += g2[ni][mi][rr];
            cs += __shfl_xor(cs, 16);
            cs += __shfl_xor(cs, 32);
            if (quad == 0)
                psum[wr * 256 + half * 128 + wc * 32 + ni * 16 + l16] = cs;
        }

        if (half == 0) __syncthreads();      // Bs(W1) ready
    }

    __syncthreads();
    if (tid < 256) Pout[(blk << 8) + tid] = psum[tid] + psum[256 + tid];
}

// ---- K2: self-scan P0 + prefixes -> h0 in LDS; layer-1 GEMM; store tanh1 ----
__global__ __launch_bounds__(512, 4) void l1_k(const bf16* __restrict__ Wb1s,
                                               uint4* __restrict__ T,
                                               const float* __restrict__ P0,
                                               float* __restrict__ Pout,
                                               const int* __restrict__ xlen) {
    __shared__ bf16 As[128 * 128];          // h0 tile
    __shared__ bf16 Bs[128 * 128];
    __shared__ float offP[256];
    __shared__ float aux[2][128];
    __shared__ float psum[512];

    const int tid  = threadIdx.x;
    const int lane = tid & 63;
    const int wid  = tid >> 6;
    const int wr   = wid >> 2;
    const int wc   = wid & 3;
    const int quad = lane >> 4;
    const int l16  = lane & 15;
    const long blk = blockIdx.x;
    const int  bb  = (int)(blk >> 4);
    const int  cc  = (int)(blk & 15);
    if ((cc << 7) >= xlen[bb]) return;

    // issue ALL independent global loads up front
    uint4 wv[4];
    {
        const uint4* W8 = (const uint4*)Wb1s;
        #pragma unroll
        for (int it = 0; it < 4; ++it) wv[it] = W8[it * 512 + tid];
    }
    uint4 tr[4];
    #pragma unroll
    for (int mi = 0; mi < 4; ++mi) tr[mi] = T[((blk * 2 + 0) * 4 + mi) * 512 + tid];

    float pv = 0.f;
    if (tid < 256) {
        #pragma unroll
        for (int cp = 0; cp < NCH - 1; ++cp) {
            float v = P0[(((long)(bb * NCH + cp)) << 8) + tid];
            pv += (cp < cc) ? v : 0.f;
        }
    }

    float g2[2][4][4];
    decode_T(tr, g2);                        // tr dies -> reuse for T half1
    #pragma unroll
    for (int mi = 0; mi < 4; ++mi) tr[mi] = T[((blk * 2 + 1) * 4 + mi) * 512 + tid];

    float pref[2][4][4], st[2];
    #pragma unroll
    for (int ni = 0; ni < 2; ++ni) {
        tile_prefix(g2[ni], pref[ni], &st[ni], quad, l16);
        if (wr == 0 && quad == 0) aux[0][wc * 32 + ni * 16 + l16] = st[ni];
    }
    // stage W0 into Bs; issue W1 loads
    #pragma unroll
    for (int it = 0; it < 4; ++it)
        *(uint4*)&Bs[(it * 512 + tid) * 8] = wv[it];
    {
        const uint4* W8 = (const uint4*)(Wb1s + 128 * HID);
        #pragma unroll
        for (int it = 0; it < 4; ++it) wv[it] = W8[it * 512 + tid];
    }
    if (tid < 256) offP[tid] = pv;
    __syncthreads();                         // BAR1: aux[0] + offP + Bs(W0)

    float p1[2][4][4];
    #pragma unroll
    for (int ni = 0; ni < 2; ++ni) {
        int col = wc * 32 + ni * 16 + l16;
        float off = offP[col];
        if (wr) off += aux[0][col];
        #pragma unroll
        for (int mi = 0; mi < 4; ++mi)
            #pragma unroll
            for (int rr = 0; rr < 4; ++rr)
                p1[ni][mi][rr] = pref[ni][mi][rr] + off;
    }

    decode_T(tr, g2);                        // T half1
    #pragma unroll
    for (int ni = 0; ni < 2; ++ni) {
        tile_prefix(g2[ni], pref[ni], &st[ni], quad, l16);
        if (wr == 0 && quad == 0) aux[1][wc * 32 + ni * 16 + l16] = st[ni];
    }
    __syncthreads();                         // BAR2: aux[1]

    #pragma unroll
    for (int ni = 0; ni < 2; ++ni) {
        int col = wc * 32 + ni * 16 + l16;
        int gsw = col >> 3, rem = col & 7;
        float off = offP[128 + col];
        if (wr) off += aux[1][col];
        #pragma unroll
        for (int mi = 0; mi < 4; ++mi)
            #pragma unroll
            for (int rr = 0; rr < 4; ++rr) {
                int row = wr * 64 + mi * 16 + quad * 4 + rr;
                float h = pref[ni][mi][rr] + off -
                          fmaxf(p1[ni][mi][rr], 0.f) * g2[ni][mi][rr];
                As[row * 128 + ((gsw ^ (row & 7)) << 3) + rem] = (bf16)h;
            }
    }
    __syncthreads();                         // BAR3: As(h0) ready

    #pragma unroll
    for (int half = 0; half < 2; ++half) {
        floatx4 acc[4][2];
        #pragma unroll
        for (int a = 0; a < 4; ++a)
            #pragma unroll
            for (int b2 = 0; b2 < 2; ++b2) acc[a][b2] = (floatx4){0.f, 0.f, 0.f, 0.f};

        gemm_tile(As, Bs, acc, wr, wc, quad, l16);

        if (half == 0) {
            __syncthreads();                 // BAR4: Bs(W0) reads done
            #pragma unroll
            for (int it = 0; it < 4; ++it)
                *(uint4*)&Bs[(it * 512 + tid) * 8] = wv[it];   // W1 -> Bs
        }

        float g2h[2][4][4];
        #pragma unroll
        for (int mi = 0; mi < 4; ++mi)
            #pragma unroll
            for (int ni = 0; ni < 2; ++ni)
                #pragma unroll
                for (int rr = 0; rr < 4; ++rr)
                    g2h[ni][mi][rr] = fast_tanh(acc[mi][ni][rr]);

        store_T_half(T, blk, half, tid, g2h);

        #pragma unroll
        for (int ni = 0; ni < 2; ++ni) {
            float cs = 0.f;
            #pragma unroll
            for (int mi = 0; mi < 4; ++mi)
                #pragma unroll
                for (int rr = 0; rr < 4; ++rr) cs += g2h[ni][mi][rr];
            cs += __shfl_xor(cs, 16);
            cs += __shfl_xor(cs, 32);
            if (quad == 0)
                psum[wr * 256 + half * 128 + wc * 32 + ni * 16 + l16] = cs;
        }

        if (half == 0) __syncthreads();      // BAR5: Bs(W1) ready
    }

    __syncthreads();                         // BAR6: psum
    if (tid < 256) Pout[(blk << 8) + tid] = psum[tid] + psum[256 + tid];
}

// ---- K3: self-scan P1 + reload tanh1 -> h1 -> fc dot -> masked loss ----
__global__ __launch_bounds__(512, 4) void loss_k(const uint4* __restrict__ T,
                                                 const float* __restrict__ P1,
                                                 const float* __restrict__ Wfc,
                                                 const int* __restrict__ xlen,
                                                 const float* __restrict__ xlab,
                                                 float* __restrict__ out) {
    __shared__ float offP[256];
    __shared__ float aux[2][128];
    __shared__ float zbuf[4][128][2];
    __shared__ float red[2];

    const int tid  = threadIdx.x;
    const int lane = tid & 63;
    const int wid  = tid >> 6;
    const int wr   = wid >> 2;
    const int wc   = wid & 3;
    const int quad = lane >> 4;
    const int l16  = lane & 15;
    const long blk = blockIdx.x;
    const int  bb  = (int)(blk >> 4);
    const int  cc  = (int)(blk & 15);
    if ((cc << 7) >= xlen[bb]) return;

    uint4 tr[4];
    #pragma unroll
    for (int mi = 0; mi < 4; ++mi) tr[mi] = T[((blk * 2 + 0) * 4 + mi) * 512 + tid];

    float pv = 0.f;
    if (tid < 256) {
        #pragma unroll
        for (int cp = 0; cp < NCH - 1; ++cp) {
            float v = P1[(((long)(bb * NCH + cp)) << 8) + tid];
            pv += (cp < cc) ? v : 0.f;
        }
    }

    float g2[2][4][4];
    decode_T(tr, g2);
    #pragma unroll
    for (int mi = 0; mi < 4; ++mi) tr[mi] = T[((blk * 2 + 1) * 4 + mi) * 512 + tid];

    float pref[2][4][4], st[2];
    #pragma unroll
    for (int ni = 0; ni < 2; ++ni) {
        tile_prefix(g2[ni], pref[ni], &st[ni], quad, l16);
        if (wr == 0 && quad == 0) aux[0][wc * 32 + ni * 16 + l16] = st[ni];
    }
    if (tid < 256) offP[tid] = pv;
    __syncthreads();                         // BAR1: aux[0] + offP

    float p1[2][4][4];
    #pragma unroll
    for (int ni = 0; ni < 2; ++ni) {
        int col = wc * 32 + ni * 16 + l16;
        float off = offP[col];
        if (wr) off += aux[0][col];
        #pragma unroll
        for (int mi = 0; mi < 4; ++mi)
            #pragma unroll
            for (int rr = 0; rr < 4; ++rr)
                p1[ni][mi][rr] = pref[ni][mi][rr] + off;
    }

    decode_T(tr, g2);
    #pragma unroll
    for (int ni = 0; ni < 2; ++ni) {
        tile_prefix(g2[ni], pref[ni], &st[ni], quad, l16);
        if (wr == 0 && quad == 0) aux[1][wc * 32 + ni * 16 + l16] = st[ni];
    }
    __syncthreads();                         // BAR2: aux[1]

    {
        float w0[2], w1[2], off[2];
        #pragma unroll
        for (int ni = 0; ni < 2; ++ni) {
            int col = wc * 32 + ni * 16 + l16;
            w0[ni] = Wfc[2 * HID + col];
            w1[ni] = Wfc[3 * HID + col];
            off[ni] = offP[128 + col];
            if (wr) off[ni] += aux[1][col];
        }
        #pragma unroll
        for (int mi = 0; mi < 4; ++mi)
            #pragma unroll
            for (int rr = 0; rr < 4; ++rr) {
                float z0 = 0.f, z1 = 0.f;
                #pragma unroll
                for (int ni = 0; ni < 2; ++ni) {
                    float h = pref[ni][mi][rr] + off[ni] -
                              fmaxf(p1[ni][mi][rr], 0.f) * g2[ni][mi][rr];
                    z0 += h * w0[ni];
                    z1 += h * w1[ni];
                }
                z0 += __shfl_xor(z0, 1); z1 += __shfl_xor(z1, 1);
                z0 += __shfl_xor(z0, 2); z1 += __shfl_xor(z1, 2);
                z0 += __shfl_xor(z0, 4); z1 += __shfl_xor(z1, 4);
                z0 += __shfl_xor(z0, 8); z1 += __shfl_xor(z1, 8);
                if (l16 == 0) {
                    int row = wr * 64 + mi * 16 + quad * 4 + rr;
                    zbuf[wc][row][0] = z0;
                    zbuf[wc][row][1] = z1;
                }
            }
    }

    __syncthreads();                         // BAR3: zbuf
    float lsum = 0.f;
    if (tid < 128) {
        int row = tid;
        float z0 = zbuf[0][row][0] + zbuf[1][row][0] + zbuf[2][row][0] + zbuf[3][row][0];
        float z1 = zbuf[0][row][1] + zbuf[1][row][1] + zbuf[2][row][1] + zbuf[3][row][1];
        float o1 = fast_sigmoid(z1 - z0);
        float sg = fast_sigmoid(o1);
        float d = xlab[bb] - sg;
        if (cc * CH + row < xlen[bb]) lsum = d * d;
        lsum += __shfl_xor(lsum, 1);
        lsum += __shfl_xor(lsum, 2);
        lsum += __shfl_xor(lsum, 4);
        lsum += __shfl_xor(lsum, 8);
        lsum += __shfl_xor(lsum, 16);
        lsum += __shfl_xor(lsum, 32);
        if (lane == 0) red[wid] = lsum;
    }
    __syncthreads();                         // BAR4: red
    if (tid == 0) atomicAdd(out, red[0] + red[1]);
}

extern "C" void kernel_launch(void* const* d_in, const int* in_sizes, int n_in,
                              void* d_out, int out_size, void* d_ws, size_t ws_size,
                              hipStream_t stream) {
    const float* x    = (const float*)d_in[0];
    const int*   xlen = (const int*)d_in[1];
    const float* xlab = (const float*)d_in[2];
    const float* Wx2h = (const float*)d_in[3];  // [2,256,128] f32
    const float* Wfc  = (const float*)d_in[4];  // [2,2,128] f32
    float* out = (float*)d_out;

    char* ws = (char*)d_ws;
    uint4* T  = (uint4*)ws;                                   // 128 MiB tanh frags
    float* P0 = (float*)(ws + (size_t)MTOT * TWOH * 2);       // 2 MiB raw chunk sums
    float* P1 = P0 + (size_t)BATCH * NCH * TWOH;              // 2 MiB
    bf16*  Wb = (bf16*)(P1 + (size_t)BATCH * NCH * TWOH);     // 128 KiB (swizzled)

    hipMemsetAsync(d_out, 0, sizeof(float), stream);
    convert_w_k<<<64, 256, 0, stream>>>(Wx2h, Wb);

    l0_k<<<MTOT / 128, 512, 0, stream>>>(x, Wb, T, P0, xlen);
    l1_k<<<MTOT / 128, 512, 0, stream>>>(Wb + (size_t)TWOH * HID, T, P0, P1, xlen);
    loss_k<<<MTOT / 128, 512, 0, stream>>>(T, P1, Wfc, xlen, xlab, out);
}

// Round 7
// 321.399 us; speedup vs baseline: 1.3009x; 1.3009x over previous
//
#include <hip/hip_runtime.h>

typedef __bf16 bf16;
typedef __bf16 bf16x8 __attribute__((ext_vector_type(8)));
typedef float floatx4 __attribute__((ext_vector_type(4)));

#define BATCH 128
#define SEQ   2048
#define HID   128
#define TWOH  256
#define CH    128
#define NCH   16
#define MTOT  (BATCH * SEQ)    // 262144

__device__ __forceinline__ float fast_tanh(float x) {
    float e = __builtin_amdgcn_exp2f(2.88539008177793f * x);
    return 1.0f - 2.0f * __builtin_amdgcn_rcpf(e + 1.0f);
}
__device__ __forceinline__ float fast_sigmoid(float x) {
    return __builtin_amdgcn_rcpf(1.0f + __builtin_amdgcn_exp2f(-1.44269504088896f * x));
}

union PK4 { unsigned long long u; bf16 h[4]; };
union PK8 { uint4 u; bf16 h[8]; };

// ---- one-time f32 -> bf16 conversion of Wx2h (both layers) ----
__global__ __launch_bounds__(256) void convert_w_k(const float* __restrict__ W,
                                                   bf16* __restrict__ Wb) {
    int i = blockIdx.x * 256 + threadIdx.x;   // 16384 float4 groups
    float4 v = ((const float4*)W)[i];
    PK4 pk;
    pk.h[0] = (bf16)v.x; pk.h[1] = (bf16)v.y;
    pk.h[2] = (bf16)v.z; pk.h[3] = (bf16)v.w;
    ((unsigned long long*)Wb)[i] = pk.u;
}

// In-tile inclusive prefix over the 128 rows of a chunk, one column set.
__device__ __forceinline__ void tile_prefix(const float g[4][4], float pref[4][4],
                                            float* stripe_tot, int quad, int l16) {
    float mibase = 0.f;
    #pragma unroll
    for (int mi = 0; mi < 4; ++mi) {
        float s0 = g[mi][0];
        float s1 = s0 + g[mi][1];
        float s2 = s1 + g[mi][2];
        float s3 = s2 + g[mi][3];
        float tot = s3, xq = tot;
        float t = __shfl_up(xq, 16);
        if (quad >= 1) xq += t;
        t = __shfl_up(xq, 32);
        if (quad >= 2) xq += t;
        float excl = mibase + xq - tot;
        pref[mi][0] = excl + s0;
        pref[mi][1] = excl + s1;
        pref[mi][2] = excl + s2;
        pref[mi][3] = excl + s3;
        mibase += __shfl(xq, 48 + l16);   // quad-3 inclusive total
    }
    *stripe_tot = mibase;
}

// ===========================================================================
// Geometry (round-3-verified): 512 threads = 8 waves, wr = wid>>2 (row
// 64-stripe), wc = wid&3 (col 32-stripe per half).
// C row = wr*64+mi*16+quad*4+rr, col = half*128+wc*32+ni*16+l16.
// tanh fragments stored to T in per-thread layout (coalesced uint4):
//   T[((blk*2+half)*4 + mi)*512 + tid] = { g2[ni=0][mi][0..3], g2[ni=1][mi][0..3] }
// EARLY-EXIT (round-5-verified): chunks with cc*128 >= xlen[bb] affect
// nothing downstream (mask zeroes their loss; later state never consumed)
// -> return before any barrier. Consumers only read predecessors cp < cc,
// which are then active too. scan_partials_k writes the prefix slot BEFORE
// accumulating a chunk's value, so garbage from inactive chunks only lands
// in slots no active consumer reads.
// ===========================================================================

// ---- K1: layer-0 GEMM; store tanh fragments + per-chunk column sums ----
__global__ __launch_bounds__(512, 4) void l0_k(const float* __restrict__ x,
                                               const bf16* __restrict__ Wb,
                                               uint4* __restrict__ T,
                                               float* __restrict__ Pout,
                                               const int* __restrict__ xlen) {
    __shared__ bf16 As[128 * 128];          // 32 KB
    __shared__ bf16 Bs[128 * 128];          // 32 KB
    __shared__ float psum[512];             // stripe sums [wr][256 cols]

    const int tid  = threadIdx.x;
    const int lane = tid & 63;
    const int wid  = tid >> 6;
    const int wr   = wid >> 2;
    const int wc   = wid & 3;
    const int quad = lane >> 4;
    const int l16  = lane & 15;
    const long blk = blockIdx.x;
    const int  bb  = (int)(blk >> 4);
    const int  cc  = (int)(blk & 15);
    if ((cc << 7) >= xlen[bb]) return;      // uniform early-exit, before barriers

    const long rowBase = blk * 128;

    // stage x chunk (f32 -> bf16, swizzled)
    {
        const float4* A4 = (const float4*)(x + rowBase * HID);
        #pragma unroll
        for (int it = 0; it < 8; ++it) {
            int i  = it * 512 + tid;
            int r  = i >> 5;
            int c4 = i & 31;
            float4 v = A4[i];
            int g = c4 >> 1, hf = c4 & 1;
            PK4 pk;
            pk.h[0] = (bf16)v.x; pk.h[1] = (bf16)v.y;
            pk.h[2] = (bf16)v.z; pk.h[3] = (bf16)v.w;
            *(unsigned long long*)&As[r * 128 + ((g ^ (r & 7)) << 3) + (hf << 2)] = pk.u;
        }
    }

    #pragma unroll
    for (int half = 0; half < 2; ++half) {
        __syncthreads();   // As ready / Bs reads of previous half done
        {
            const uint4* W8 = (const uint4*)(Wb + (size_t)half * 128 * HID);
            #pragma unroll
            for (int it = 0; it < 4; ++it) {
                int i = it * 512 + tid;
                int r = i >> 4;
                int g = i & 15;
                uint4 v = W8[i];
                *(uint4*)&Bs[r * 128 + ((g ^ (r & 7)) << 3)] = v;
            }
        }
        __syncthreads();

        floatx4 acc[4][2];
        #pragma unroll
        for (int a = 0; a < 4; ++a)
            #pragma unroll
            for (int b2 = 0; b2 < 2; ++b2) acc[a][b2] = (floatx4){0.f, 0.f, 0.f, 0.f};

        #pragma unroll
        for (int kk = 0; kk < 128; kk += 32) {
            bf16x8 af[4], bfr[2];
            int kg = (kk >> 3) + quad;
            #pragma unroll
            for (int mi = 0; mi < 4; ++mi) {
                int r = wr * 64 + mi * 16 + l16;
                af[mi] = *(const bf16x8*)&As[r * 128 + ((kg ^ (r & 7)) << 3)];
            }
            #pragma unroll
            for (int ni = 0; ni < 2; ++ni) {
                int n = wc * 32 + ni * 16 + l16;
                bfr[ni] = *(const bf16x8*)&Bs[n * 128 + ((kg ^ (n & 7)) << 3)];
            }
            #pragma unroll
            for (int mi = 0; mi < 4; ++mi)
                #pragma unroll
                for (int ni = 0; ni < 2; ++ni)
                    acc[mi][ni] = __builtin_amdgcn_mfma_f32_16x16x32_bf16(
                        af[mi], bfr[ni], acc[mi][ni], 0, 0, 0);
        }

        float g2[2][4][4];   // [ni][mi][rr]
        #pragma unroll
        for (int mi = 0; mi < 4; ++mi)
            #pragma unroll
            for (int ni = 0; ni < 2; ++ni)
                #pragma unroll
                for (int rr = 0; rr < 4; ++rr)
                    g2[ni][mi][rr] = fast_tanh(acc[mi][ni][rr]);

        // store tanh fragments (coalesced)
        #pragma unroll
        for (int mi = 0; mi < 4; ++mi) {
            PK8 p;
            #pragma unroll
            for (int rr = 0; rr < 4; ++rr) {
                p.h[rr]     = (bf16)g2[0][mi][rr];
                p.h[4 + rr] = (bf16)g2[1][mi][rr];
            }
            T[((blk * 2 + half) * 4 + mi) * 512 + tid] = p.u;
        }

        // per-column stripe sums
        #pragma unroll
        for (int ni = 0; ni < 2; ++ni) {
            float cs = 0.f;
            #pragma unroll
            for (int mi = 0; mi < 4; ++mi)
                #pragma unroll
                for (int rr = 0; rr < 4; ++rr) cs += g2[ni][mi][rr];
            cs += __shfl_xor(cs, 16);
            cs += __shfl_xor(cs, 32);
            if (quad == 0)
                psum[wr * 256 + half * 128 + wc * 32 + ni * 16 + l16] = cs;
        }
    }

    __syncthreads();
    if (tid < 256) Pout[(blk << 8) + tid] = psum[tid] + psum[256 + tid];
}

// in-place exclusive scan over the NCH chunks, per (b, ch).
// Writes slot c BEFORE accumulating v[c] -> inactive-chunk garbage only
// reaches slots with index > last active chunk, which are never read.
__global__ __launch_bounds__(256) void scan_partials_k(float* __restrict__ P) {
    int ch = threadIdx.x;
    long b = blockIdx.x;
    float v[NCH];
    #pragma unroll
    for (int c = 0; c < NCH; ++c) v[c] = P[((b * NCH + c) << 8) + ch];
    float run = 0.f;
    #pragma unroll
    for (int c = 0; c < NCH; ++c) {
        float t = v[c];
        P[((b * NCH + c) << 8) + ch] = run;
        run += t;
    }
}

// ---- K3: reload tanh0, prefixes -> h0 in LDS; layer-1 GEMM; store tanh1 ----
__global__ __launch_bounds__(512, 4) void l1_k(const bf16* __restrict__ Wb1,
                                               uint4* __restrict__ T,
                                               const float* __restrict__ P0,
                                               float* __restrict__ Pout,
                                               const int* __restrict__ xlen) {
    __shared__ bf16 As[128 * 128];          // h0 tile, 32 KB
    __shared__ bf16 Bs[128 * 128];
    __shared__ float auxp[128];
    __shared__ float psum[512];

    const int tid  = threadIdx.x;
    const int lane = tid & 63;
    const int wid  = tid >> 6;
    const int wr   = wid >> 2;
    const int wc   = wid & 3;
    const int quad = lane >> 4;
    const int l16  = lane & 15;
    const long blk = blockIdx.x;
    const int  bb  = (int)(blk >> 4);
    const int  cc  = (int)(blk & 15);
    if ((cc << 7) >= xlen[bb]) return;

    float p1[2][4][4];   // half-0 global-inclusive prefixes (s1n)

    // ---- half 0 of tanh0: prefix -> p1 ----
    {
        float g2[2][4][4];
        #pragma unroll
        for (int mi = 0; mi < 4; ++mi) {
            PK8 p;
            p.u = T[((blk * 2 + 0) * 4 + mi) * 512 + tid];
            #pragma unroll
            for (int rr = 0; rr < 4; ++rr) {
                g2[0][mi][rr] = (float)p.h[rr];
                g2[1][mi][rr] = (float)p.h[4 + rr];
            }
        }
        float pref[2][4][4], st[2];
        #pragma unroll
        for (int ni = 0; ni < 2; ++ni) {
            tile_prefix(g2[ni], pref[ni], &st[ni], quad, l16);
            if (wr == 0 && quad == 0) auxp[wc * 32 + ni * 16 + l16] = st[ni];
        }
        __syncthreads();
        #pragma unroll
        for (int ni = 0; ni < 2; ++ni) {
            int col = wc * 32 + ni * 16 + l16;
            float off = P0[(blk << 8) + col];
            if (wr) off += auxp[col];
            #pragma unroll
            for (int mi = 0; mi < 4; ++mi)
                #pragma unroll
                for (int rr = 0; rr < 4; ++rr)
                    p1[ni][mi][rr] = pref[ni][mi][rr] + off;
        }
    }
    __syncthreads();   // auxp reuse guard

    // ---- half 1 of tanh0: prefix -> h0 -> As (swizzled bf16) ----
    {
        float g2[2][4][4];
        #pragma unroll
        for (int mi = 0; mi < 4; ++mi) {
            PK8 p;
            p.u = T[((blk * 2 + 1) * 4 + mi) * 512 + tid];
            #pragma unroll
            for (int rr = 0; rr < 4; ++rr) {
                g2[0][mi][rr] = (float)p.h[rr];
                g2[1][mi][rr] = (float)p.h[4 + rr];
            }
        }
        float pref[2][4][4], st[2];
        #pragma unroll
        for (int ni = 0; ni < 2; ++ni) {
            tile_prefix(g2[ni], pref[ni], &st[ni], quad, l16);
            if (wr == 0 && quad == 0) auxp[wc * 32 + ni * 16 + l16] = st[ni];
        }
        __syncthreads();
        #pragma unroll
        for (int ni = 0; ni < 2; ++ni) {
            int col = wc * 32 + ni * 16 + l16;
            int gsw = col >> 3, rem = col & 7;
            float off = P0[(blk << 8) + 128 + col];
            if (wr) off += auxp[col];
            #pragma unroll
            for (int mi = 0; mi < 4; ++mi)
                #pragma unroll
                for (int rr = 0; rr < 4; ++rr) {
                    int row = wr * 64 + mi * 16 + quad * 4 + rr;
                    float h = pref[ni][mi][rr] + off -
                              fmaxf(p1[ni][mi][rr], 0.f) * g2[ni][mi][rr];
                    As[row * 128 + ((gsw ^ (row & 7)) << 3) + rem] = (bf16)h;
                }
        }
    }

    // ---- layer-1 GEMM + tanh -> store tanh1 + column sums ----
    #pragma unroll
    for (int half = 0; half < 2; ++half) {
        __syncthreads();   // As ready (half0) / Bs reads done (half1)
        {
            const uint4* W8 = (const uint4*)(Wb1 + (size_t)half * 128 * HID);
            #pragma unroll
            for (int it = 0; it < 4; ++it) {
                int i = it * 512 + tid;
                int r = i >> 4;
                int g = i & 15;
                uint4 v = W8[i];
                *(uint4*)&Bs[r * 128 + ((g ^ (r & 7)) << 3)] = v;
            }
        }
        __syncthreads();

        floatx4 acc[4][2];
        #pragma unroll
        for (int a = 0; a < 4; ++a)
            #pragma unroll
            for (int b2 = 0; b2 < 2; ++b2) acc[a][b2] = (floatx4){0.f, 0.f, 0.f, 0.f};

        #pragma unroll
        for (int kk = 0; kk < 128; kk += 32) {
            bf16x8 af[4], bfr[2];
            int kg = (kk >> 3) + quad;
            #pragma unroll
            for (int mi = 0; mi < 4; ++mi) {
                int r = wr * 64 + mi * 16 + l16;
                af[mi] = *(const bf16x8*)&As[r * 128 + ((kg ^ (r & 7)) << 3)];
            }
            #pragma unroll
            for (int ni = 0; ni < 2; ++ni) {
                int n = wc * 32 + ni * 16 + l16;
                bfr[ni] = *(const bf16x8*)&Bs[n * 128 + ((kg ^ (n & 7)) << 3)];
            }
            #pragma unroll
            for (int mi = 0; mi < 4; ++mi)
                #pragma unroll
                for (int ni = 0; ni < 2; ++ni)
                    acc[mi][ni] = __builtin_amdgcn_mfma_f32_16x16x32_bf16(
                        af[mi], bfr[ni], acc[mi][ni], 0, 0, 0);
        }

        float g2[2][4][4];
        #pragma unroll
        for (int mi = 0; mi < 4; ++mi)
            #pragma unroll
            for (int ni = 0; ni < 2; ++ni)
                #pragma unroll
                for (int rr = 0; rr < 4; ++rr)
                    g2[ni][mi][rr] = fast_tanh(acc[mi][ni][rr]);

        #pragma unroll
        for (int mi = 0; mi < 4; ++mi) {
            PK8 p;
            #pragma unroll
            for (int rr = 0; rr < 4; ++rr) {
                p.h[rr]     = (bf16)g2[0][mi][rr];
                p.h[4 + rr] = (bf16)g2[1][mi][rr];
            }
            T[((blk * 2 + half) * 4 + mi) * 512 + tid] = p.u;
        }

        #pragma unroll
        for (int ni = 0; ni < 2; ++ni) {
            float cs = 0.f;
            #pragma unroll
            for (int mi = 0; mi < 4; ++mi)
                #pragma unroll
                for (int rr = 0; rr < 4; ++rr) cs += g2[ni][mi][rr];
            cs += __shfl_xor(cs, 16);
            cs += __shfl_xor(cs, 32);
            if (quad == 0)
                psum[wr * 256 + half * 128 + wc * 32 + ni * 16 + l16] = cs;
        }
    }

    __syncthreads();
    if (tid < 256) Pout[(blk << 8) + tid] = psum[tid] + psum[256 + tid];
}

// ---- K5: reload tanh1, prefixes -> h1 -> fc dot -> masked loss ----
__global__ __launch_bounds__(512, 4) void loss_k(const uint4* __restrict__ T,
                                                 const float* __restrict__ P1,
                                                 const float* __restrict__ Wfc,
                                                 const int* __restrict__ xlen,
                                                 const float* __restrict__ xlab,
                                                 float* __restrict__ out) {
    __shared__ float auxp[128];
    __shared__ float zbuf[4][128][2];
    __shared__ float red[2];

    const int tid  = threadIdx.x;
    const int lane = tid & 63;
    const int wid  = tid >> 6;
    const int wr   = wid >> 2;
    const int wc   = wid & 3;
    const int quad = lane >> 4;
    const int l16  = lane & 15;
    const long blk = blockIdx.x;
    const int  bb  = (int)(blk >> 4);
    const int  cc  = (int)(blk & 15);
    if ((cc << 7) >= xlen[bb]) return;

    float p1[2][4][4];

    // half 0: prefix -> p1
    {
        float g2[2][4][4];
        #pragma unroll
        for (int mi = 0; mi < 4; ++mi) {
            PK8 p;
            p.u = T[((blk * 2 + 0) * 4 + mi) * 512 + tid];
            #pragma unroll
            for (int rr = 0; rr < 4; ++rr) {
                g2[0][mi][rr] = (float)p.h[rr];
                g2[1][mi][rr] = (float)p.h[4 + rr];
            }
        }
        float pref[2][4][4], st[2];
        #pragma unroll
        for (int ni = 0; ni < 2; ++ni) {
            tile_prefix(g2[ni], pref[ni], &st[ni], quad, l16);
            if (wr == 0 && quad == 0) auxp[wc * 32 + ni * 16 + l16] = st[ni];
        }
        __syncthreads();
        #pragma unroll
        for (int ni = 0; ni < 2; ++ni) {
            int col = wc * 32 + ni * 16 + l16;
            float off = P1[(blk << 8) + col];
            if (wr) off += auxp[col];
            #pragma unroll
            for (int mi = 0; mi < 4; ++mi)
                #pragma unroll
                for (int rr = 0; rr < 4; ++rr)
                    p1[ni][mi][rr] = pref[ni][mi][rr] + off;
        }
    }
    __syncthreads();

    // half 1: prefix -> h1 -> fc dot
    {
        float g2[2][4][4];
        #pragma unroll
        for (int mi = 0; mi < 4; ++mi) {
            PK8 p;
            p.u = T[((blk * 2 + 1) * 4 + mi) * 512 + tid];
            #pragma unroll
            for (int rr = 0; rr < 4; ++rr) {
                g2[0][mi][rr] = (float)p.h[rr];
                g2[1][mi][rr] = (float)p.h[4 + rr];
            }
        }
        float pref[2][4][4], st[2];
        #pragma unroll
        for (int ni = 0; ni < 2; ++ni) {
            tile_prefix(g2[ni], pref[ni], &st[ni], quad, l16);
            if (wr == 0 && quad == 0) auxp[wc * 32 + ni * 16 + l16] = st[ni];
        }
        __syncthreads();

        float w0[2], w1[2], off[2];
        #pragma unroll
        for (int ni = 0; ni < 2; ++ni) {
            int col = wc * 32 + ni * 16 + l16;
            w0[ni] = Wfc[2 * HID + col];
            w1[ni] = Wfc[3 * HID + col];
            off[ni] = P1[(blk << 8) + 128 + col];
            if (wr) off[ni] += auxp[col];
        }
        #pragma unroll
        for (int mi = 0; mi < 4; ++mi)
            #pragma unroll
            for (int rr = 0; rr < 4; ++rr) {
                float z0 = 0.f, z1 = 0.f;
                #pragma unroll
                for (int ni = 0; ni < 2; ++ni) {
                    float h = pref[ni][mi][rr] + off[ni] -
                              fmaxf(p1[ni][mi][rr], 0.f) * g2[ni][mi][rr];
                    z0 += h * w0[ni];
                    z1 += h * w1[ni];
                }
                z0 += __shfl_xor(z0, 1); z1 += __shfl_xor(z1, 1);
                z0 += __shfl_xor(z0, 2); z1 += __shfl_xor(z1, 2);
                z0 += __shfl_xor(z0, 4); z1 += __shfl_xor(z1, 4);
                z0 += __shfl_xor(z0, 8); z1 += __shfl_xor(z1, 8);
                if (l16 == 0) {
                    int row = wr * 64 + mi * 16 + quad * 4 + rr;
                    zbuf[wc][row][0] = z0;
                    zbuf[wc][row][1] = z1;
                }
            }
    }

    __syncthreads();
    float lsum = 0.f;
    if (tid < 128) {
        int row = tid;
        float z0 = zbuf[0][row][0] + zbuf[1][row][0] + zbuf[2][row][0] + zbuf[3][row][0];
        float z1 = zbuf[0][row][1] + zbuf[1][row][1] + zbuf[2][row][1] + zbuf[3][row][1];
        float o1 = fast_sigmoid(z1 - z0);
        float sg = fast_sigmoid(o1);
        float d = xlab[bb] - sg;
        if (cc * CH + row < xlen[bb]) lsum = d * d;
        lsum += __shfl_xor(lsum, 1);
        lsum += __shfl_xor(lsum, 2);
        lsum += __shfl_xor(lsum, 4);
        lsum += __shfl_xor(lsum, 8);
        lsum += __shfl_xor(lsum, 16);
        lsum += __shfl_xor(lsum, 32);
        if (lane == 0) red[wid] = lsum;
    }
    __syncthreads();
    if (tid == 0) atomicAdd(out, red[0] + red[1]);
}

extern "C" void kernel_launch(void* const* d_in, const int* in_sizes, int n_in,
                              void* d_out, int out_size, void* d_ws, size_t ws_size,
                              hipStream_t stream) {
    const float* x    = (const float*)d_in[0];
    const int*   xlen = (const int*)d_in[1];
    const float* xlab = (const float*)d_in[2];
    const float* Wx2h = (const float*)d_in[3];  // [2,256,128] f32
    const float* Wfc  = (const float*)d_in[4];  // [2,2,128] f32
    float* out = (float*)d_out;

    char* ws = (char*)d_ws;
    uint4* T  = (uint4*)ws;                                   // 128 MiB tanh frags
    float* P0 = (float*)(ws + (size_t)MTOT * TWOH * 2);       // 2 MiB
    float* P1 = P0 + (size_t)BATCH * NCH * TWOH;              // 2 MiB
    bf16*  Wb = (bf16*)(P1 + (size_t)BATCH * NCH * TWOH);     // 128 KiB

    hipMemsetAsync(d_out, 0, sizeof(float), stream);
    convert_w_k<<<64, 256, 0, stream>>>(Wx2h, Wb);

    l0_k<<<MTOT / 128, 512, 0, stream>>>(x, Wb, T, P0, xlen);
    scan_partials_k<<<BATCH, 256, 0, stream>>>(P0);
    l1_k<<<MTOT / 128, 512, 0, stream>>>(Wb + (size_t)TWOH * HID, T, P0, P1, xlen);
    scan_partials_k<<<BATCH, 256, 0, stream>>>(P1);
    loss_k<<<MTOT / 128, 512, 0, stream>>>(T, P1, Wfc, xlen, xlab, out);
}

// Round 9
// 320.970 us; speedup vs baseline: 1.3026x; 1.0013x over previous
//
#include <hip/hip_runtime.h>

typedef __bf16 bf16;
typedef __bf16 bf16x8 __attribute__((ext_vector_type(8)));
typedef float floatx4 __attribute__((ext_vector_type(4)));

#define BATCH 128
#define SEQ   2048
#define HID   128
#define TWOH  256
#define CH    128
#define NCH   16
#define MTOT  (BATCH * SEQ)    // 262144

__device__ __forceinline__ float fast_tanh(float x) {
    float e = __builtin_amdgcn_exp2f(2.88539008177793f * x);
    return 1.0f - 2.0f * __builtin_amdgcn_rcpf(e + 1.0f);
}
__device__ __forceinline__ float fast_sigmoid(float x) {
    return __builtin_amdgcn_rcpf(1.0f + __builtin_amdgcn_exp2f(-1.44269504088896f * x));
}

union PK4 { unsigned long long u; bf16 h[4]; };
union PK8 { uint4 u; bf16 h[8]; };

// ---- one-time f32 -> bf16 conversion of Wx2h (both layers) ----
__global__ __launch_bounds__(256) void convert_w_k(const float* __restrict__ W,
                                                   bf16* __restrict__ Wb) {
    int i = blockIdx.x * 256 + threadIdx.x;   // 16384 float4 groups
    float4 v = ((const float4*)W)[i];
    PK4 pk;
    pk.h[0] = (bf16)v.x; pk.h[1] = (bf16)v.y;
    pk.h[2] = (bf16)v.z; pk.h[3] = (bf16)v.w;
    ((unsigned long long*)Wb)[i] = pk.u;
}

// In-tile inclusive prefix over the 128 rows of a chunk, one column set.
__device__ __forceinline__ void tile_prefix(const float g[4][4], float pref[4][4],
                                            float* stripe_tot, int quad, int l16) {
    float mibase = 0.f;
    #pragma unroll
    for (int mi = 0; mi < 4; ++mi) {
        float s0 = g[mi][0];
        float s1 = s0 + g[mi][1];
        float s2 = s1 + g[mi][2];
        float s3 = s2 + g[mi][3];
        float tot = s3, xq = tot;
        float t = __shfl_up(xq, 16);
        if (quad >= 1) xq += t;
        t = __shfl_up(xq, 32);
        if (quad >= 2) xq += t;
        float excl = mibase + xq - tot;
        pref[mi][0] = excl + s0;
        pref[mi][1] = excl + s1;
        pref[mi][2] = excl + s2;
        pref[mi][3] = excl + s3;
        mibase += __shfl(xq, 48 + l16);   // quad-3 inclusive total
    }
    *stripe_tot = mibase;
}

// ===========================================================================
// Geometry (round-3-verified): 512 threads = 8 waves, wr = wid>>2 (row
// 64-stripe), wc = wid&3 (col 32-stripe per half).
// C row = wr*64+mi*16+quad*4+rr, col = half*128+wc*32+ni*16+l16.
// tanh fragments stored to T in per-thread layout (coalesced uint4).
// EARLY-EXIT (round-5/7-verified): chunks with cc*128 >= xlen[bb] skipped.
// K-SPLIT (this round): W staged as 16KB K-halves (Bs[128][64]) -> LDS 50KB
// -> 3 blocks/CU instead of 2. MFMA accumulation order unchanged
// (kk = 0,32,64,96 ascending per half) -> bit-identical results.
// ===========================================================================

// ---- K1: layer-0 GEMM; store tanh fragments + per-chunk column sums ----
__global__ __launch_bounds__(512, 4) void l0_k(const float* __restrict__ x,
                                               const bf16* __restrict__ Wb,
                                               uint4* __restrict__ T,
                                               float* __restrict__ Pout,
                                               const int* __restrict__ xlen) {
    __shared__ bf16 As[128 * 128];          // 32 KB  (x tile)
    __shared__ bf16 Bs[128 * 64];           // 16 KB  (W K-half)
    __shared__ float psum[512];             // 2 KB

    const int tid  = threadIdx.x;
    const int lane = tid & 63;
    const int wid  = tid >> 6;
    const int wr   = wid >> 2;
    const int wc   = wid & 3;
    const int quad = lane >> 4;
    const int l16  = lane & 15;
    const long blk = blockIdx.x;
    const int  bb  = (int)(blk >> 4);
    const int  cc  = (int)(blk & 15);
    if ((cc << 7) >= xlen[bb]) return;      // uniform early-exit, before barriers

    const long rowBase = blk * 128;

    // stage x chunk (f32 -> bf16, swizzled into As[128][128], 16 groups of 8)
    {
        const float4* A4 = (const float4*)(x + rowBase * HID);
        #pragma unroll
        for (int it = 0; it < 8; ++it) {
            int i  = it * 512 + tid;
            int r  = i >> 5;
            int c4 = i & 31;
            float4 v = A4[i];
            int g = c4 >> 1, hf = c4 & 1;
            PK4 pk;
            pk.h[0] = (bf16)v.x; pk.h[1] = (bf16)v.y;
            pk.h[2] = (bf16)v.z; pk.h[3] = (bf16)v.w;
            *(unsigned long long*)&As[r * 128 + ((g ^ (r & 7)) << 3) + (hf << 2)] = pk.u;
        }
    }

    #pragma unroll
    for (int half = 0; half < 2; ++half) {
        floatx4 acc[4][2];
        #pragma unroll
        for (int a = 0; a < 4; ++a)
            #pragma unroll
            for (int b2 = 0; b2 < 2; ++b2) acc[a][b2] = (floatx4){0.f, 0.f, 0.f, 0.f};

        #pragma unroll
        for (int kp = 0; kp < 2; ++kp) {
            if (half + kp) __syncthreads();  // prior Bs reads done
            // stage W quarter (half, kp): rows 0..127 of this half, cols kp*64..+64
            {
                const uint4* W8 = (const uint4*)(Wb + (size_t)half * 128 * HID + kp * 64);
                #pragma unroll
                for (int it = 0; it < 2; ++it) {
                    int i = it * 512 + tid;
                    int r = i >> 3;          // 0..127
                    int g = i & 7;           // col-group within K-half
                    uint4 v = W8[r * 16 + g];   // row stride = 128 bf16 = 16 uint4
                    *(uint4*)&Bs[r * 64 + ((g ^ (r & 7)) << 3)] = v;
                }
            }
            __syncthreads();                 // Bs ready (+As ready at first)

            #pragma unroll
            for (int kk2 = 0; kk2 < 2; ++kk2) {
                int kgl = kk2 * 4 + quad;    // local K-group in Bs (0..7)
                int kg  = kp * 8 + kgl;      // global K-group in As (0..15)
                bf16x8 af[4], bfr[2];
                #pragma unroll
                for (int mi = 0; mi < 4; ++mi) {
                    int r = wr * 64 + mi * 16 + l16;
                    af[mi] = *(const bf16x8*)&As[r * 128 + ((kg ^ (r & 7)) << 3)];
                }
                #pragma unroll
                for (int ni = 0; ni < 2; ++ni) {
                    int n = wc * 32 + ni * 16 + l16;
                    bfr[ni] = *(const bf16x8*)&Bs[n * 64 + ((kgl ^ (n & 7)) << 3)];
                }
                #pragma unroll
                for (int mi = 0; mi < 4; ++mi)
                    #pragma unroll
                    for (int ni = 0; ni < 2; ++ni)
                        acc[mi][ni] = __builtin_amdgcn_mfma_f32_16x16x32_bf16(
                            af[mi], bfr[ni], acc[mi][ni], 0, 0, 0);
            }
        }

        float g2[2][4][4];   // [ni][mi][rr]
        #pragma unroll
        for (int mi = 0; mi < 4; ++mi)
            #pragma unroll
            for (int ni = 0; ni < 2; ++ni)
                #pragma unroll
                for (int rr = 0; rr < 4; ++rr)
                    g2[ni][mi][rr] = fast_tanh(acc[mi][ni][rr]);

        // store tanh fragments (coalesced); overlaps next restage barrier
        #pragma unroll
        for (int mi = 0; mi < 4; ++mi) {
            PK8 p;
            #pragma unroll
            for (int rr = 0; rr < 4; ++rr) {
                p.h[rr]     = (bf16)g2[0][mi][rr];
                p.h[4 + rr] = (bf16)g2[1][mi][rr];
            }
            T[((blk * 2 + half) * 4 + mi) * 512 + tid] = p.u;
        }

        // per-column stripe sums
        #pragma unroll
        for (int ni = 0; ni < 2; ++ni) {
            float cs = 0.f;
            #pragma unroll
            for (int mi = 0; mi < 4; ++mi)
                #pragma unroll
                for (int rr = 0; rr < 4; ++rr) cs += g2[ni][mi][rr];
            cs += __shfl_xor(cs, 16);
            cs += __shfl_xor(cs, 32);
            if (quad == 0)
                psum[wr * 256 + half * 128 + wc * 32 + ni * 16 + l16] = cs;
        }
    }

    __syncthreads();
    if (tid < 256) Pout[(blk << 8) + tid] = psum[tid] + psum[256 + tid];
}

// in-place exclusive scan over the NCH chunks, per (b, ch).
__global__ __launch_bounds__(256) void scan_partials_k(float* __restrict__ P) {
    int ch = threadIdx.x;
    long b = blockIdx.x;
    float v[NCH];
    #pragma unroll
    for (int c = 0; c < NCH; ++c) v[c] = P[((b * NCH + c) << 8) + ch];
    float run = 0.f;
    #pragma unroll
    for (int c = 0; c < NCH; ++c) {
        float t = v[c];
        P[((b * NCH + c) << 8) + ch] = run;
        run += t;
    }
}

// ---- K3: reload tanh0, prefixes -> h0 in LDS; layer-1 GEMM; store tanh1 ----
__global__ __launch_bounds__(512, 4) void l1_k(const bf16* __restrict__ Wb1,
                                               uint4* __restrict__ T,
                                               const float* __restrict__ P0,
                                               float* __restrict__ Pout,
                                               const int* __restrict__ xlen) {
    __shared__ bf16 As[128 * 128];          // h0 tile, 32 KB
    __shared__ bf16 Bs[128 * 64];           // 16 KB
    __shared__ float auxp[128];
    __shared__ float psum[512];

    const int tid  = threadIdx.x;
    const int lane = tid & 63;
    const int wid  = tid >> 6;
    const int wr   = wid >> 2;
    const int wc   = wid & 3;
    const int quad = lane >> 4;
    const int l16  = lane & 15;
    const long blk = blockIdx.x;
    const int  bb  = (int)(blk >> 4);
    const int  cc  = (int)(blk & 15);
    if ((cc << 7) >= xlen[bb]) return;

    float p1[2][4][4];   // half-0 global-inclusive prefixes (s1n)

    // ---- half 0 of tanh0: prefix -> p1 ----
    {
        float g2[2][4][4];
        #pragma unroll
        for (int mi = 0; mi < 4; ++mi) {
            PK8 p;
            p.u = T[((blk * 2 + 0) * 4 + mi) * 512 + tid];
            #pragma unroll
            for (int rr = 0; rr < 4; ++rr) {
                g2[0][mi][rr] = (float)p.h[rr];
                g2[1][mi][rr] = (float)p.h[4 + rr];
            }
        }
        float pref[2][4][4], st[2];
        #pragma unroll
        for (int ni = 0; ni < 2; ++ni) {
            tile_prefix(g2[ni], pref[ni], &st[ni], quad, l16);
            if (wr == 0 && quad == 0) auxp[wc * 32 + ni * 16 + l16] = st[ni];
        }
        __syncthreads();
        #pragma unroll
        for (int ni = 0; ni < 2; ++ni) {
            int col = wc * 32 + ni * 16 + l16;
            float off = P0[(blk << 8) + col];
            if (wr) off += auxp[col];
            #pragma unroll
            for (int mi = 0; mi < 4; ++mi)
                #pragma unroll
                for (int rr = 0; rr < 4; ++rr)
                    p1[ni][mi][rr] = pref[ni][mi][rr] + off;
        }
    }
    __syncthreads();   // auxp reuse guard

    // ---- half 1 of tanh0: prefix -> h0 -> As (swizzled bf16) ----
    {
        float g2[2][4][4];
        #pragma unroll
        for (int mi = 0; mi < 4; ++mi) {
            PK8 p;
            p.u = T[((blk * 2 + 1) * 4 + mi) * 512 + tid];
            #pragma unroll
            for (int rr = 0; rr < 4; ++rr) {
                g2[0][mi][rr] = (float)p.h[rr];
                g2[1][mi][rr] = (float)p.h[4 + rr];
            }
        }
        float pref[2][4][4], st[2];
        #pragma unroll
        for (int ni = 0; ni < 2; ++ni) {
            tile_prefix(g2[ni], pref[ni], &st[ni], quad, l16);
            if (wr == 0 && quad == 0) auxp[wc * 32 + ni * 16 + l16] = st[ni];
        }
        __syncthreads();
        #pragma unroll
        for (int ni = 0; ni < 2; ++ni) {
            int col = wc * 32 + ni * 16 + l16;
            int gsw = col >> 3, rem = col & 7;
            float off = P0[(blk << 8) + 128 + col];
            if (wr) off += auxp[col];
            #pragma unroll
            for (int mi = 0; mi < 4; ++mi)
                #pragma unroll
                for (int rr = 0; rr < 4; ++rr) {
                    int row = wr * 64 + mi * 16 + quad * 4 + rr;
                    float h = pref[ni][mi][rr] + off -
                              fmaxf(p1[ni][mi][rr], 0.f) * g2[ni][mi][rr];
                    As[row * 128 + ((gsw ^ (row & 7)) << 3) + rem] = (bf16)h;
                }
        }
    }

    // ---- layer-1 GEMM + tanh -> store tanh1 + column sums (K-split Bs) ----
    #pragma unroll
    for (int half = 0; half < 2; ++half) {
        floatx4 acc[4][2];
        #pragma unroll
        for (int a = 0; a < 4; ++a)
            #pragma unroll
            for (int b2 = 0; b2 < 2; ++b2) acc[a][b2] = (floatx4){0.f, 0.f, 0.f, 0.f};

        #pragma unroll
        for (int kp = 0; kp < 2; ++kp) {
            if (half + kp) __syncthreads();  // prior Bs reads done
            {
                const uint4* W8 = (const uint4*)(Wb1 + (size_t)half * 128 * HID + kp * 64);
                #pragma unroll
                for (int it = 0; it < 2; ++it) {
                    int i = it * 512 + tid;
                    int r = i >> 3;
                    int g = i & 7;
                    uint4 v = W8[r * 16 + g];
                    *(uint4*)&Bs[r * 64 + ((g ^ (r & 7)) << 3)] = v;
                }
            }
            __syncthreads();                 // Bs ready (+As h0-writes at first)

            #pragma unroll
            for (int kk2 = 0; kk2 < 2; ++kk2) {
                int kgl = kk2 * 4 + quad;
                int kg  = kp * 8 + kgl;
                bf16x8 af[4], bfr[2];
                #pragma unroll
                for (int mi = 0; mi < 4; ++mi) {
                    int r = wr * 64 + mi * 16 + l16;
                    af[mi] = *(const bf16x8*)&As[r * 128 + ((kg ^ (r & 7)) << 3)];
                }
                #pragma unroll
                for (int ni = 0; ni < 2; ++ni) {
                    int n = wc * 32 + ni * 16 + l16;
                    bfr[ni] = *(const bf16x8*)&Bs[n * 64 + ((kgl ^ (n & 7)) << 3)];
                }
                #pragma unroll
                for (int mi = 0; mi < 4; ++mi)
                    #pragma unroll
                    for (int ni = 0; ni < 2; ++ni)
                        acc[mi][ni] = __builtin_amdgcn_mfma_f32_16x16x32_bf16(
                            af[mi], bfr[ni], acc[mi][ni], 0, 0, 0);
            }
        }

        float g2[2][4][4];
        #pragma unroll
        for (int mi = 0; mi < 4; ++mi)
            #pragma unroll
            for (int ni = 0; ni < 2; ++ni)
                #pragma unroll
                for (int rr = 0; rr < 4; ++rr)
                    g2[ni][mi][rr] = fast_tanh(acc[mi][ni][rr]);

        #pragma unroll
        for (int mi = 0; mi < 4; ++mi) {
            PK8 p;
            #pragma unroll
            for (int rr = 0; rr < 4; ++rr) {
                p.h[rr]     = (bf16)g2[0][mi][rr];
                p.h[4 + rr] = (bf16)g2[1][mi][rr];
            }
            T[((blk * 2 + half) * 4 + mi) * 512 + tid] = p.u;
        }

        #pragma unroll
        for (int ni = 0; ni < 2; ++ni) {
            float cs = 0.f;
            #pragma unroll
            for (int mi = 0; mi < 4; ++mi)
                #pragma unroll
                for (int rr = 0; rr < 4; ++rr) cs += g2[ni][mi][rr];
            cs += __shfl_xor(cs, 16);
            cs += __shfl_xor(cs, 32);
            if (quad == 0)
                psum[wr * 256 + half * 128 + wc * 32 + ni * 16 + l16] = cs;
        }
    }

    __syncthreads();
    if (tid < 256) Pout[(blk << 8) + tid] = psum[tid] + psum[256 + tid];
}

// ---- K5: reload tanh1, prefixes -> h1 -> fc dot -> masked loss ----
__global__ __launch_bounds__(512, 4) void loss_k(const uint4* __restrict__ T,
                                                 const float* __restrict__ P1,
                                                 const float* __restrict__ Wfc,
                                                 const int* __restrict__ xlen,
                                                 const float* __restrict__ xlab,
                                                 float* __restrict__ out) {
    __shared__ float auxp[128];
    __shared__ float zbuf[4][128][2];
    __shared__ float red[2];

    const int tid  = threadIdx.x;
    const int lane = tid & 63;
    const int wid  = tid >> 6;
    const int wr   = wid >> 2;
    const int wc   = wid & 3;
    const int quad = lane >> 4;
    const int l16  = lane & 15;
    const long blk = blockIdx.x;
    const int  bb  = (int)(blk >> 4);
    const int  cc  = (int)(blk & 15);
    if ((cc << 7) >= xlen[bb]) return;

    float p1[2][4][4];

    // half 0: prefix -> p1
    {
        float g2[2][4][4];
        #pragma unroll
        for (int mi = 0; mi < 4; ++mi) {
            PK8 p;
            p.u = T[((blk * 2 + 0) * 4 + mi) * 512 + tid];
            #pragma unroll
            for (int rr = 0; rr < 4; ++rr) {
                g2[0][mi][rr] = (float)p.h[rr];
                g2[1][mi][rr] = (float)p.h[4 + rr];
            }
        }
        float pref[2][4][4], st[2];
        #pragma unroll
        for (int ni = 0; ni < 2; ++ni) {
            tile_prefix(g2[ni], pref[ni], &st[ni], quad, l16);
            if (wr == 0 && quad == 0) auxp[wc * 32 + ni * 16 + l16] = st[ni];
        }
        __syncthreads();
        #pragma unroll
        for (int ni = 0; ni < 2; ++ni) {
            int col = wc * 32 + ni * 16 + l16;
            float off = P1[(blk << 8) + col];
            if (wr) off += auxp[col];
            #pragma unroll
            for (int mi = 0; mi < 4; ++mi)
                #pragma unroll
                for (int rr = 0; rr < 4; ++rr)
                    p1[ni][mi][rr] = pref[ni][mi][rr] + off;
        }
    }
    __syncthreads();

    // half 1: prefix -> h1 -> fc dot
    {
        float g2[2][4][4];
        #pragma unroll
        for (int mi = 0; mi < 4; ++mi) {
            PK8 p;
            p.u = T[((blk * 2 + 1) * 4 + mi) * 512 + tid];
            #pragma unroll
            for (int rr = 0; rr < 4; ++rr) {
                g2[0][mi][rr] = (float)p.h[rr];
                g2[1][mi][rr] = (float)p.h[4 + rr];
            }
        }
        float pref[2][4][4], st[2];
        #pragma unroll
        for (int ni = 0; ni < 2; ++ni) {
            tile_prefix(g2[ni], pref[ni], &st[ni], quad, l16);
            if (wr == 0 && quad == 0) auxp[wc * 32 + ni * 16 + l16] = st[ni];
        }
        __syncthreads();

        float w0[2], w1[2], off[2];
        #pragma unroll
        for (int ni = 0; ni < 2; ++ni) {
            int col = wc * 32 + ni * 16 + l16;
            w0[ni] = Wfc[2 * HID + col];
            w1[ni] = Wfc[3 * HID + col];
            off[ni] = P1[(blk << 8) + 128 + col];
            if (wr) off[ni] += auxp[col];
        }
        #pragma unroll
        for (int mi = 0; mi < 4; ++mi)
            #pragma unroll
            for (int rr = 0; rr < 4; ++rr) {
                float z0 = 0.f, z1 = 0.f;
                #pragma unroll
                for (int ni = 0; ni < 2; ++ni) {
                    float h = pref[ni][mi][rr] + off[ni] -
                              fmaxf(p1[ni][mi][rr], 0.f) * g2[ni][mi][rr];
                    z0 += h * w0[ni];
                    z1 += h * w1[ni];
                }
                z0 += __shfl_xor(z0, 1); z1 += __shfl_xor(z1, 1);
                z0 += __shfl_xor(z0, 2); z1 += __shfl_xor(z1, 2);
                z0 += __shfl_xor(z0, 4); z1 += __shfl_xor(z1, 4);
                z0 += __shfl_xor(z0, 8); z1 += __shfl_xor(z1, 8);
                if (l16 == 0) {
                    int row = wr * 64 + mi * 16 + quad * 4 + rr;
                    zbuf[wc][row][0] = z0;
                    zbuf[wc][row][1] = z1;
                }
            }
    }

    __syncthreads();
    float lsum = 0.f;
    if (tid < 128) {
        int row = tid;
        float z0 = zbuf[0][row][0] + zbuf[1][row][0] + zbuf[2][row][0] + zbuf[3][row][0];
        float z1 = zbuf[0][row][1] + zbuf[1][row][1] + zbuf[2][row][1] + zbuf[3][row][1];
        float o1 = fast_sigmoid(z1 - z0);
        float sg = fast_sigmoid(o1);
        float d = xlab[bb] - sg;
        if (cc * CH + row < xlen[bb]) lsum = d * d;
        lsum += __shfl_xor(lsum, 1);
        lsum += __shfl_xor(lsum, 2);
        lsum += __shfl_xor(lsum, 4);
        lsum += __shfl_xor(lsum, 8);
        lsum += __shfl_xor(lsum, 16);
        lsum += __shfl_xor(lsum, 32);
        if (lane == 0) red[wid] = lsum;
    }
    __syncthreads();
    if (tid == 0) atomicAdd(out, red[0] + red[1]);
}

extern "C" void kernel_launch(void* const* d_in, const int* in_sizes, int n_in,
                              void* d_out, int out_size, void* d_ws, size_t ws_size,
                              hipStream_t stream) {
    const float* x    = (const float*)d_in[0];
    const int*   xlen = (const int*)d_in[1];
    const float* xlab = (const float*)d_in[2];
    const float* Wx2h = (const float*)d_in[3];  // [2,256,128] f32
    const float* Wfc  = (const float*)d_in[4];  // [2,2,128] f32
    float* out = (float*)d_out;

    char* ws = (char*)d_ws;
    uint4* T  = (uint4*)ws;                                   // 128 MiB tanh frags
    float* P0 = (float*)(ws + (size_t)MTOT * TWOH * 2);       // 2 MiB
    float* P1 = P0 + (size_t)BATCH * NCH * TWOH;              // 2 MiB
    bf16*  Wb = (bf16*)(P1 + (size_t)BATCH * NCH * TWOH);     // 128 KiB

    hipMemsetAsync(d_out, 0, sizeof(float), stream);
    convert_w_k<<<64, 256, 0, stream>>>(Wx2h, Wb);

    l0_k<<<MTOT / 128, 512, 0, stream>>>(x, Wb, T, P0, xlen);
    scan_partials_k<<<BATCH, 256, 0, stream>>>(P0);
    l1_k<<<MTOT / 128, 512, 0, stream>>>(Wb + (size_t)TWOH * HID, T, P0, P1, xlen);
    scan_partials_k<<<BATCH, 256, 0, stream>>>(P1);
    loss_k<<<MTOT / 128, 512, 0, stream>>>(T, P1, Wfc, xlen, xlab, out);
}